// Round 10
// baseline (518.054 us; speedup 1.0000x reference)
//
#include <hip/hip_runtime.h>
#include <stdint.h>

#define NB 4
#define SEQ 16384
#define CH 512
#define NH 16
#define HD 32
#define QKVC 1536
#define MROWS (NB * SEQ) /* 65536 */

typedef unsigned short u16;
typedef __attribute__((ext_vector_type(8))) short bf16x8;
typedef __attribute__((ext_vector_type(4))) float f32x4;

__device__ __forceinline__ float bf2f(u16 u) {
  union { unsigned int i; float f; } c; c.i = ((unsigned int)u) << 16; return c.f;
}
__device__ __forceinline__ u16 f2bf(float f) {
  union { float f; unsigned int i; } c; c.f = f;
  return (u16)((c.i + 0x7fffu + ((c.i >> 16) & 1u)) >> 16);
}

__device__ __forceinline__ void async16(const u16* g, u16* l) {
  __builtin_amdgcn_global_load_lds((const __attribute__((address_space(1))) void*)g,
                                   (__attribute__((address_space(3))) void*)l,
                                   16, 0, 0);
}

// ---------------------------------------------------------------------------
// Kernel 0 (tiny): cast qkv_weight / proj_weight f32 -> bf16, zero vk acc.
// ---------------------------------------------------------------------------
__global__ void prep_kernel(const float* __restrict__ qw,
                            const float* __restrict__ pw,
                            u16* __restrict__ qwb,
                            u16* __restrict__ pwb,
                            float* __restrict__ vk) {
  int gid = blockIdx.x * blockDim.x + threadIdx.x;
  int stride = gridDim.x * blockDim.x;

  const float4* q4 = (const float4*)qw;
  ushort4* qwb4 = (ushort4*)qwb;
  for (int i = gid; i < (QKVC * CH / 4); i += stride) {
    float4 v = q4[i];
    ushort4 o; o.x = f2bf(v.x); o.y = f2bf(v.y); o.z = f2bf(v.z); o.w = f2bf(v.w);
    qwb4[i] = o;
  }
  const float4* p4 = (const float4*)pw;
  ushort4* pwb4 = (ushort4*)pwb;
  for (int i = gid; i < (CH * CH / 4); i += stride) {
    float4 v = p4[i];
    ushort4 o; o.x = f2bf(v.x); o.y = f2bf(v.y); o.z = f2bf(v.z); o.w = f2bf(v.w);
    pwb4[i] = o;
  }
  float4 z; z.x = 0.f; z.y = 0.f; z.z = 0.f; z.w = 0.f;
  float4* vk4 = (float4*)vk;
  for (int i = gid; i < (NB * NH * 33 * 32 / 4); i += stride) vk4[i] = z;
}

// ---------------------------------------------------------------------------
// 8-phase 256x256 bf16 GEMM. Grid-tiled 2D, BK=64, 8 waves, per-wave 128x64.
// XOR-swizzled LDS. Counted vmcnt per k-tile; direct stores.
// F32A: A is f32, reg-staged (f32x4 loads -> RNE cvt -> swizzled ds_write),
//   2 k-tiles ahead. RULE-#20 FIX: the k-loop is manually unrolled x2 with
//   NAMED register sets asetA/asetB (tile t -> set t&1) so no runtime index
//   ever touches the staging registers (r8/r9: aset[kt&1] with a rolled loop
//   -> local memory -> 430MB scratch traffic, 356us).
// !F32A: A bf16 via global_load_lds.
// ---------------------------------------------------------------------------
template <int N_DIM, bool F32A, bool FINAL>
__global__ __launch_bounds__(512, 1) void gemm8p_kernel(
    const void* __restrict__ Ain, const u16* __restrict__ Bm,
    void* __restrict__ Out, u16* __restrict__ OutK, u16* __restrict__ OutV,
    const float* __restrict__ bias) {
  __shared__ __align__(16) u16 lds[65536];  // 128 KiB

  const float* A32 = (const float*)Ain;
  const u16* A16 = (const u16*)Ain;

  const int tid = threadIdx.x;
  const int lane = tid & 63;
  const int w = tid >> 6;   // 0..7
  const int wr = w >> 2;    // 0..1  (M half)
  const int wc = w & 3;     // 0..3  (N quarter)
  const int fr = lane & 15;
  const int g = lane >> 4;
  const int xr = (fr & 7) << 3;  // read-side XOR (u16 units)

  // XCD-bijective block swizzle (nwg % 8 == 0 for both shapes)
  const int gridX = N_DIM / 256;
  const int nwg = gridX * (MROWS / 256);
  int bid = blockIdx.y * gridX + blockIdx.x;
  bid = (bid & 7) * (nwg >> 3) + (bid >> 3);
  const long row0 = (long)(bid / gridX) * 256;
  const long col0 = (long)(bid % gridX) * 256;

  const int trow = tid >> 3;                                        // 0..63
  const int c8lin = (tid & 7) * 8;                                  // linear col
  const int tcol = c8lin ^ ((trow & 7) << 3);                       // pre-swizzled
  const int aswz = tcol;                                            // write-side swz

#define STAGE_A16(kt_, h_)                                                    \
  do {                                                                        \
    u16* lb_ = &lds[(((kt_) & 1) * 2 + (h_)) * 8192 + w * 512];               \
    const u16* ga_ = A16 + (size_t)(row0 + (h_) * 128 + trow) * 512 +         \
                     (kt_) * 64 + tcol;                                       \
    async16(ga_, lb_);                                                        \
    async16(ga_ + 64 * 512, lb_ + 4096);                                      \
  } while (0)

#define STAGE_B(kt_, h_)                                                      \
  do {                                                                        \
    u16* lb_ = &lds[32768 + (((kt_) & 1) * 2 + (h_)) * 8192 + w * 512];       \
    const u16* gb_ = Bm + (size_t)(col0 + (h_) * 128 + trow) * 512 +          \
                     (kt_) * 64 + tcol;                                       \
    async16(gb_, lb_);                                                        \
    async16(gb_ + 64 * 512, lb_ + 4096);                                      \
  } while (0)

  // f32-A: issue 8 f32x4 loads for tile kt into NAMED set S_
#define LOADA(kt_, S_)                                                        \
  do {                                                                        \
    _Pragma("unroll") for (int r4 = 0; r4 < 4; ++r4) {                        \
      const float* ga_ = A32 + (size_t)(row0 + r4 * 64 + trow) * 512 +        \
                         (kt_) * 64 + c8lin;                                  \
      S_[r4][0] = *(const f32x4*)ga_;                                         \
      S_[r4][1] = *(const f32x4*)(ga_ + 4);                                   \
    }                                                                         \
  } while (0)

  // convert + swizzled LDS write for tile kt from NAMED set S_
#define WRITEA(kt_, S_)                                                       \
  do {                                                                        \
    _Pragma("unroll") for (int r4 = 0; r4 < 4; ++r4) {                        \
      bf16x8 wv_;                                                             \
      _Pragma("unroll") for (int j = 0; j < 4; ++j) {                         \
        wv_[j] = (short)f2bf(S_[r4][0][j]);                                   \
        wv_[4 + j] = (short)f2bf(S_[r4][1][j]);                               \
      }                                                                       \
      const int h_ = r4 >> 1;                                                 \
      const int r_ = (r4 & 1) * 64 + trow;                                    \
      *(bf16x8*)&lds[(((kt_) & 1) * 2 + h_) * 8192 + r_ * 64 + aswz] = wv_;   \
    }                                                                         \
  } while (0)

  f32x4 asetA[4][2], asetB[4][2];  // two named in-flight A k-tiles (F32A only)
  f32x4 acc[8][4];
#pragma unroll
  for (int m = 0; m < 8; m++)
#pragma unroll
    for (int n = 0; n < 4; n++) {
      f32x4 z = {0.f, 0.f, 0.f, 0.f};
      acc[m][n] = z;
    }
  bf16x8 a[4][2], b[4][2];

  // ---- prologue (tile t lives in LDS slot & reg-set t&1)
  if constexpr (F32A) {
    LOADA(0, asetA);
    asm volatile("s_waitcnt vmcnt(0)" ::: "memory");
    WRITEA(0, asetA);
    LOADA(1, asetB);
    STAGE_B(0, 0); STAGE_B(0, 1); STAGE_B(1, 0);
    asm volatile("s_waitcnt vmcnt(2) lgkmcnt(0)" ::: "memory");
  } else {
    STAGE_B(0, 0); STAGE_A16(0, 0); STAGE_B(0, 1); STAGE_A16(0, 1);
    STAGE_B(1, 0); STAGE_A16(1, 0);
    asm volatile("s_waitcnt vmcnt(4)" ::: "memory");
  }
  __builtin_amdgcn_s_barrier();

  // one k-tile: 4 phases. SL_ = set receiving LOADA(kt+2); SW_ = set holding
  // tile kt+1 for WRITEA. (tile t -> set t&1: even kt loads even tile kt+2
  // into asetA and writes odd tile kt+1 from asetB; odd kt the converse.)
#define KTBODY(kt_, SL_, SW_)                                                 \
  {                                                                           \
    const int abase = (((kt_) & 1) * 2 + wr) * 8192;                          \
    const int bbase = 32768 + (((kt_) & 1) * 2 + (wc >> 1)) * 8192 +          \
                      (wc & 1) * 4096;                                        \
    /* -- ph0: read A m0-3 + B n0-1; LOADA(kt+2); stage B hi(kt+1) */         \
    _Pragma("unroll") for (int m = 0; m < 4; ++m)                             \
      _Pragma("unroll") for (int kk = 0; kk < 2; ++kk)                        \
        a[m][kk] = *(const bf16x8*)&lds[abase + (m * 16 + fr) * 64 +          \
                                        ((kk * 32 + g * 8) ^ xr)];            \
    _Pragma("unroll") for (int n = 0; n < 2; ++n)                             \
      _Pragma("unroll") for (int kk = 0; kk < 2; ++kk)                        \
        b[n][kk] = *(const bf16x8*)&lds[bbase + (n * 16 + fr) * 64 +          \
                                        ((kk * 32 + g * 8) ^ xr)];            \
    if constexpr (F32A) {                                                     \
      if ((kt_) < 6) LOADA((kt_) + 2, SL_);                                   \
    }                                                                         \
    if ((kt_) < 7) STAGE_B((kt_) + 1, 1);                                     \
    __builtin_amdgcn_s_barrier();                                             \
    asm volatile("s_waitcnt lgkmcnt(0)" ::: "memory");                        \
    __builtin_amdgcn_s_setprio(1);                                            \
    _Pragma("unroll") for (int m = 0; m < 4; ++m)                             \
      _Pragma("unroll") for (int n = 0; n < 2; ++n)                           \
        _Pragma("unroll") for (int kk = 0; kk < 2; ++kk)                      \
          acc[m][n] = __builtin_amdgcn_mfma_f32_16x16x32_bf16(                \
              a[m][kk], b[n][kk], acc[m][n], 0, 0, 0);                        \
    __builtin_amdgcn_s_setprio(0);                                            \
    __builtin_amdgcn_s_barrier();                                             \
    /* -- ph1: read B n2-3; write/stage A(kt+1) */                            \
    _Pragma("unroll") for (int n = 0; n < 2; ++n)                             \
      _Pragma("unroll") for (int kk = 0; kk < 2; ++kk)                        \
        b[2 + n][kk] = *(const bf16x8*)&lds[bbase + ((n + 2) * 16 + fr) * 64 +\
                                            ((kk * 32 + g * 8) ^ xr)];        \
    if constexpr (F32A) {                                                     \
      if ((kt_) < 7) WRITEA((kt_) + 1, SW_);                                  \
    } else {                                                                  \
      if ((kt_) < 7) STAGE_A16((kt_) + 1, 1);                                 \
    }                                                                         \
    __builtin_amdgcn_s_barrier();                                             \
    asm volatile("s_waitcnt lgkmcnt(0)" ::: "memory");                        \
    __builtin_amdgcn_s_setprio(1);                                            \
    _Pragma("unroll") for (int m = 0; m < 4; ++m)                             \
      _Pragma("unroll") for (int n = 0; n < 2; ++n)                           \
        _Pragma("unroll") for (int kk = 0; kk < 2; ++kk)                      \
          acc[m][2 + n] = __builtin_amdgcn_mfma_f32_16x16x32_bf16(            \
              a[m][kk], b[2 + n][kk], acc[m][2 + n], 0, 0, 0);                \
    __builtin_amdgcn_s_setprio(0);                                            \
    __builtin_amdgcn_s_barrier();                                             \
    /* -- ph2: read A m4-7; stage B lo(kt+2) */                               \
    _Pragma("unroll") for (int m = 0; m < 4; ++m)                             \
      _Pragma("unroll") for (int kk = 0; kk < 2; ++kk)                        \
        a[m][kk] = *(const bf16x8*)&lds[abase + ((m + 4) * 16 + fr) * 64 +    \
                                        ((kk * 32 + g * 8) ^ xr)];            \
    if ((kt_) < 6) STAGE_B((kt_) + 2, 0);                                     \
    __builtin_amdgcn_s_barrier();                                             \
    asm volatile("s_waitcnt lgkmcnt(0)" ::: "memory");                        \
    __builtin_amdgcn_s_setprio(1);                                            \
    _Pragma("unroll") for (int m = 0; m < 4; ++m)                             \
      _Pragma("unroll") for (int n = 0; n < 2; ++n)                           \
        _Pragma("unroll") for (int kk = 0; kk < 2; ++kk)                      \
          acc[4 + m][2 + n] = __builtin_amdgcn_mfma_f32_16x16x32_bf16(        \
              a[m][kk], b[2 + n][kk], acc[4 + m][2 + n], 0, 0, 0);            \
    __builtin_amdgcn_s_setprio(0);                                            \
    __builtin_amdgcn_s_barrier();                                             \
    /* -- ph3: (proj: stage A lo(kt+2)); counted vmcnt gate */                \
    if constexpr (F32A) {                                                     \
      if ((kt_) < 6) {                                                        \
        asm volatile("s_waitcnt vmcnt(2)" ::: "memory");                      \
      } else {                                                                \
        asm volatile("s_waitcnt vmcnt(0)" ::: "memory");                      \
      }                                                                       \
    } else {                                                                  \
      if ((kt_) < 6) {                                                        \
        STAGE_A16((kt_) + 2, 0);                                              \
        asm volatile("s_waitcnt vmcnt(4)" ::: "memory");                      \
      } else {                                                                \
        asm volatile("s_waitcnt vmcnt(0)" ::: "memory");                      \
      }                                                                       \
    }                                                                         \
    __builtin_amdgcn_s_barrier();                                             \
    __builtin_amdgcn_s_setprio(1);                                            \
    _Pragma("unroll") for (int m = 0; m < 4; ++m)                             \
      _Pragma("unroll") for (int n = 0; n < 2; ++n)                           \
        _Pragma("unroll") for (int kk = 0; kk < 2; ++kk)                      \
          acc[4 + m][n] = __builtin_amdgcn_mfma_f32_16x16x32_bf16(            \
              a[m][kk], b[n][kk], acc[4 + m][n], 0, 0, 0);                    \
    __builtin_amdgcn_s_setprio(0);                                            \
    __builtin_amdgcn_s_barrier();                                             \
  }

  for (int kt2 = 0; kt2 < 8; kt2 += 2) {
    KTBODY(kt2, asetA, asetB);
    KTBODY(kt2 + 1, asetB, asetA);
  }
#undef KTBODY
#undef STAGE_A16
#undef STAGE_B
#undef LOADA
#undef WRITEA

  // epilogue: direct stores.
  const long rbase = row0 + wr * 128;
  if constexpr (!FINAL) {
    const int bufi = (int)(col0 >> 9);  // 256-tile never straddles 512 boundary
    u16* ob = bufi == 0 ? (u16*)Out : (bufi == 1 ? OutK : OutV);
    const bool dorelu = bufi < 2;
    const long cbase = (col0 & 511) + wc * 64;
#pragma unroll
    for (int m = 0; m < 8; ++m)
#pragma unroll
      for (int n = 0; n < 4; ++n)
#pragma unroll
        for (int j = 0; j < 4; ++j) {
          long gr = rbase + m * 16 + g * 4 + j;
          long gc = cbase + n * 16 + fr;
          float v = acc[m][n][j];
          if (dorelu) v = fmaxf(v, 0.f);
          ob[gr * 512 + gc] = f2bf(v);
        }
  } else {
    const long cbase = col0 + wc * 64;
#pragma unroll
    for (int m = 0; m < 8; ++m)
#pragma unroll
      for (int n = 0; n < 4; ++n)
#pragma unroll
        for (int j = 0; j < 4; ++j) {
          long gr = rbase + m * 16 + g * 4 + j;
          long gc = cbase + n * 16 + fr;
          ((float*)Out)[gr * N_DIM + gc] = acc[m][n][j] + bias[gc];
        }
  }
}

// ---------------------------------------------------------------------------
// Kernel 2 (MFMA): vk[b,h,c,d] = sum_n v[n,h,c]*k[n,h,d], row 32 = sum_n k.
// ---------------------------------------------------------------------------
__global__ __launch_bounds__(256) void vk_kernel(const u16* __restrict__ kb,
                                                 const u16* __restrict__ vb,
                                                 float* __restrict__ vk) {
  __shared__ u16 tile[4][64 * 64];   // 32 KB
  __shared__ float red[1056];        // 4.2 KB block accumulator

  const int tid = threadIdx.x;
  const int lane = tid & 63;
  const int w = tid >> 6;

  for (int i = tid; i < 1056; i += 256) red[i] = 0.f;
  __syncthreads();

  const int bh = blockIdx.x >> 4;
  const int split = blockIdx.x & 15;
  const int b = bh >> 4, h = bh & 15;

  const int s = lane & 7;   // column segment: 0-3 -> k, 4-7 -> v
  const int rl = lane >> 3; // row within 8-row staging group
  const u16* src = (s & 4) ? vb : kb;
  const size_t gbase = (size_t)b * SEQ * 512 + h * 32 + (s & 3) * 8;

  f32x4 acc[2][2];
  f32x4 accs[2];
#pragma unroll
  for (int tc = 0; tc < 2; tc++) {
    f32x4 z = {0.f, 0.f, 0.f, 0.f};
    accs[tc] = z;
#pragma unroll
    for (int td = 0; td < 2; td++) acc[tc][td] = z;
  }
  bf16x8 ones;
#pragma unroll
  for (int j = 0; j < 8; j++) ones[j] = (short)0x3F80;  // bf16 1.0

  const int m = lane & 15;
  const int g = lane >> 4;
  u16* tw = tile[w];
  const int n0w = split * 1024 + w * 256;

  for (int t = 0; t < 4; ++t) {
    const int nt = n0w + t * 64;
#pragma unroll
    for (int p = 0; p < 8; ++p)
      async16(src + gbase + (size_t)(nt + p * 8 + rl) * 512, &tw[p * 512]);
    asm volatile("s_waitcnt vmcnt(0)" ::: "memory");
#pragma unroll
    for (int kk = 0; kk < 2; ++kk) {
      bf16x8 av[2], bk[2];
#pragma unroll
      for (int tc = 0; tc < 2; tc++)
#pragma unroll
        for (int j = 0; j < 8; j++)
          av[tc][j] = (short)tw[(kk * 32 + g * 8 + j) * 64 + 32 + tc * 16 + m];
#pragma unroll
      for (int td = 0; td < 2; td++)
#pragma unroll
        for (int j = 0; j < 8; j++)
          bk[td][j] = (short)tw[(kk * 32 + g * 8 + j) * 64 + td * 16 + m];
#pragma unroll
      for (int tc = 0; tc < 2; tc++)
#pragma unroll
        for (int td = 0; td < 2; td++)
          acc[tc][td] = __builtin_amdgcn_mfma_f32_16x16x32_bf16(av[tc], bk[td], acc[tc][td], 0, 0, 0);
#pragma unroll
      for (int td = 0; td < 2; td++)
        accs[td] = __builtin_amdgcn_mfma_f32_16x16x32_bf16(ones, bk[td], accs[td], 0, 0, 0);
    }
  }

#pragma unroll
  for (int tc = 0; tc < 2; tc++)
#pragma unroll
    for (int td = 0; td < 2; td++)
#pragma unroll
      for (int j = 0; j < 4; j++)
        atomicAdd(&red[(tc * 16 + g * 4 + j) * 32 + td * 16 + m], acc[tc][td][j]);
  if (lane < 16) {
#pragma unroll
    for (int td = 0; td < 2; td++)
      atomicAdd(&red[1024 + td * 16 + lane], accs[td][0]);
  }
  __syncthreads();
  float* dst = vk + (size_t)bh * 1056;
  for (int i = tid; i < 1056; i += 256) atomicAdd(&dst[i], red[i]);
}

// ---------------------------------------------------------------------------
// Kernel 3: vk_q + divide -> proj_input (bf16). Thread owns one (n,h) pair.
// ---------------------------------------------------------------------------
__global__ __launch_bounds__(256) void vkq_kernel(const u16* __restrict__ qb,
                                                  const float* __restrict__ vk,
                                                  u16* __restrict__ pi) {
  __shared__ float vkl[8 * 1056];  // 33.8 KB
  __shared__ u16 ob[32 * 256];     // 16 KB output bounce

  const int tid = threadIdx.x;
  const int chunk = blockIdx.x & 511;
  const int hh = (blockIdx.x >> 9) & 1;
  const int b = blockIdx.x >> 10;
  const int n0 = chunk * 32;

  const float* vg = vk + (size_t)(b * NH + hh * 8) * 1056;
  for (int i = tid; i < 8 * 1056; i += 256) vkl[i] = vg[i];
  __syncthreads();

  const int nl = tid & 31;
  const int hl = tid >> 5;
  const float* vkh = &vkl[hl * 1056];

  const u16* qp = qb + ((size_t)b * SEQ + n0 + nl) * 512 + (hh * 8 + hl) * 32;
  float qf[32];
#pragma unroll
  for (int s2 = 0; s2 < 4; ++s2) {
    bf16x8 qv = *(const bf16x8*)(qp + s2 * 8);
#pragma unroll
    for (int j = 0; j < 8; ++j) qf[s2 * 8 + j] = bf2f((u16)qv[j]);
  }

  float num[32];
#pragma unroll
  for (int c = 0; c < 32; ++c) {
    float a = 0.f;
#pragma unroll
    for (int d4 = 0; d4 < 8; ++d4) {
      f32x4 vv = *(const f32x4*)&vkh[c * 32 + d4 * 4];
      a = fmaf(qf[d4 * 4 + 0], vv[0], a);
      a = fmaf(qf[d4 * 4 + 1], vv[1], a);
      a = fmaf(qf[d4 * 4 + 2], vv[2], a);
      a = fmaf(qf[d4 * 4 + 3], vv[3], a);
    }
    num[c] = a;
  }
  float den = 0.f;
#pragma unroll
  for (int d4 = 0; d4 < 8; ++d4) {
    f32x4 vv = *(const f32x4*)&vkh[32 * 32 + d4 * 4];
    den = fmaf(qf[d4 * 4 + 0], vv[0], den);
    den = fmaf(qf[d4 * 4 + 1], vv[1], den);
    den = fmaf(qf[d4 * 4 + 2], vv[2], den);
    den = fmaf(qf[d4 * 4 + 3], vv[3], den);
  }
  const float r = 1.0f / (den + 1e-15f);
#pragma unroll
  for (int c = 0; c < 32; ++c) ob[nl * 256 + hl * 32 + c] = f2bf(num[c] * r);
  __syncthreads();

  u16* pg = pi + ((size_t)b * SEQ + n0) * CH + hh * 256;
  for (int i = tid; i < 1024; i += 256) {
    const int n = i >> 5;
    const int u = i & 31;
    *(bf16x8*)(pg + (size_t)n * CH + u * 8) = *(const bf16x8*)&ob[i * 8];
  }
}

// ---------------------------------------------------------------------------
extern "C" void kernel_launch(void* const* d_in, const int* in_sizes, int n_in,
                              void* d_out, int out_size, void* d_ws, size_t ws_size,
                              hipStream_t stream) {
  const float* x = (const float*)d_in[0];
  const float* qw = (const float*)d_in[1];
  const float* pw = (const float*)d_in[2];
  const float* bias = (const float*)d_in[3];

  char* ws = (char*)d_ws;
  u16* qb = (u16*)(ws);                       // 65536*512*2 = 67108864 B
  u16* kb = (u16*)(ws + 67108864);            // 67108864 B
  u16* vb = (u16*)(ws + 134217728);           // 67108864 B
  u16* pi = (u16*)(ws + 201326592);           // 67108864 B
  u16* qwb = (u16*)(ws + 268435456);          // 1536*512*2 = 1572864 B
  u16* pwb = (u16*)(ws + 270008320);          // 512*512*2  =  524288 B
  float* vk = (float*)(ws + 270532608);       // 64*1056*4  =  270336 B

  prep_kernel<<<256, 256, 0, stream>>>(qw, pw, qwb, pwb, vk);
  gemm8p_kernel<QKVC, true, false>
      <<<dim3(QKVC / 256, MROWS / 256), 512, 0, stream>>>(x, qwb, qb, kb, vb, nullptr);
  vk_kernel<<<NB * NH * 16, 256, 0, stream>>>(kb, vb, vk);
  vkq_kernel<<<NB * 2 * (SEQ / 32), 256, 0, stream>>>(qb, vk, pi);
  gemm8p_kernel<CH, false, true>
      <<<dim3(CH / 256, MROWS / 256), 512, 0, stream>>>(pi, pwb, d_out, nullptr, nullptr, bias);
}

// Round 11
// 320.221 us; speedup vs baseline: 1.6178x; 1.6178x over previous
//
#include <hip/hip_runtime.h>
#include <stdint.h>

#define NB 4
#define SEQ 16384
#define CH 512
#define NH 16
#define HD 32
#define QKVC 1536
#define MROWS (NB * SEQ) /* 65536 */

typedef unsigned short u16;
typedef __attribute__((ext_vector_type(8))) short bf16x8;
typedef __attribute__((ext_vector_type(4))) float f32x4;

__device__ __forceinline__ float bf2f(u16 u) {
  union { unsigned int i; float f; } c; c.i = ((unsigned int)u) << 16; return c.f;
}
__device__ __forceinline__ u16 f2bf(float f) {
  union { float f; unsigned int i; } c; c.f = f;
  return (u16)((c.i + 0x7fffu + ((c.i >> 16) & 1u)) >> 16);
}

__device__ __forceinline__ void async16(const u16* g, u16* l) {
  __builtin_amdgcn_global_load_lds((const __attribute__((address_space(1))) void*)g,
                                   (__attribute__((address_space(3))) void*)l,
                                   16, 0, 0);
}

// ---------------------------------------------------------------------------
// Kernel 0: cast x / qkv_weight / proj_weight f32 -> bf16, zero vk accumulator
// ---------------------------------------------------------------------------
__global__ void prep_kernel(const float* __restrict__ x,
                            const float* __restrict__ qw,
                            const float* __restrict__ pw,
                            u16* __restrict__ xb,
                            u16* __restrict__ qwb,
                            u16* __restrict__ pwb,
                            float* __restrict__ vk) {
  int gid = blockIdx.x * blockDim.x + threadIdx.x;
  int stride = gridDim.x * blockDim.x;

  const float4* x4 = (const float4*)x;
  ushort4* xb4 = (ushort4*)xb;
  for (int i = gid; i < (MROWS * CH / 4); i += stride) {
    float4 v = x4[i];
    ushort4 o; o.x = f2bf(v.x); o.y = f2bf(v.y); o.z = f2bf(v.z); o.w = f2bf(v.w);
    xb4[i] = o;
  }
  const float4* q4 = (const float4*)qw;
  ushort4* qwb4 = (ushort4*)qwb;
  for (int i = gid; i < (QKVC * CH / 4); i += stride) {
    float4 v = q4[i];
    ushort4 o; o.x = f2bf(v.x); o.y = f2bf(v.y); o.z = f2bf(v.z); o.w = f2bf(v.w);
    qwb4[i] = o;
  }
  const float4* p4 = (const float4*)pw;
  ushort4* pwb4 = (ushort4*)pwb;
  for (int i = gid; i < (CH * CH / 4); i += stride) {
    float4 v = p4[i];
    ushort4 o; o.x = f2bf(v.x); o.y = f2bf(v.y); o.z = f2bf(v.z); o.w = f2bf(v.w);
    pwb4[i] = o;
  }
  float4 z; z.x = 0.f; z.y = 0.f; z.z = 0.f; z.w = 0.f;
  float4* vk4 = (float4*)vk;
  for (int i = gid; i < (NB * NH * 33 * 32 / 4); i += stride) vk4[i] = z;
}

// ---------------------------------------------------------------------------
// 8-phase 256x256 bf16 GEMM (r3/r7 schedule, best measured). Grid-tiled 2D,
// BK=64, 8 waves (2Mx4N), per-wave 128x64. XOR-swizzled LDS both sides.
// Counted vmcnt(4) per k-tile; direct-store epilogue.
// SPLIT3: output cols [0,512)->OutQ relu, [512,1024)->OutK relu,
// [1024,1536)->OutV, each ldc=512 bf16. FINAL: f32 + bias, ldc=N_DIM.
// ---------------------------------------------------------------------------
template <int N_DIM, bool SPLIT3, bool FINAL>
__global__ __launch_bounds__(512) void gemm8p_kernel(
    const u16* __restrict__ A, const u16* __restrict__ Bm,
    void* __restrict__ Out, u16* __restrict__ OutK, u16* __restrict__ OutV,
    const float* __restrict__ bias) {
  __shared__ __align__(16) u16 lds[65536];  // 128 KiB

  const int tid = threadIdx.x;
  const int lane = tid & 63;
  const int w = tid >> 6;   // 0..7
  const int wr = w >> 2;    // 0..1  (M half)
  const int wc = w & 3;     // 0..3  (N quarter)
  const int fr = lane & 15;
  const int g = lane >> 4;
  const int xr = (fr & 7) << 3;  // read-side XOR (u16 units)

  // XCD-bijective block swizzle (nwg % 8 == 0 for both shapes)
  const int gridX = N_DIM / 256;
  const int nwg = gridX * (MROWS / 256);
  int bid = blockIdx.y * gridX + blockIdx.x;
  bid = (bid & 7) * (nwg >> 3) + (bid >> 3);
  const long row0 = (long)(bid / gridX) * 256;
  const long col0 = (long)(bid % gridX) * 256;

  // staging: source element pre-swizzled so swizzled read returns linear data.
  const int trow = tid >> 3;                                        // 0..63
  const int tcol = ((tid & 7) * 8) ^ (((tid >> 3) & 7) << 3);       // u16 units

#define STAGE_A(kt_, h_)                                                      \
  do {                                                                        \
    u16* lb_ = &lds[(((kt_) & 1) * 2 + (h_)) * 8192 + w * 512];               \
    const u16* ga_ = A + (size_t)(row0 + (h_) * 128 + trow) * 512 +           \
                     (kt_) * 64 + tcol;                                       \
    async16(ga_, lb_);                                                        \
    async16(ga_ + 64 * 512, lb_ + 4096);                                      \
  } while (0)

#define STAGE_B(kt_, h_)                                                      \
  do {                                                                        \
    u16* lb_ = &lds[32768 + (((kt_) & 1) * 2 + (h_)) * 8192 + w * 512];       \
    const u16* gb_ = Bm + (size_t)(col0 + (h_) * 128 + trow) * 512 +          \
                     (kt_) * 64 + tcol;                                       \
    async16(gb_, lb_);                                                        \
    async16(gb_ + 64 * 512, lb_ + 4096);                                      \
  } while (0)

  f32x4 acc[8][4];
#pragma unroll
  for (int m = 0; m < 8; m++)
#pragma unroll
    for (int n = 0; n < 4; n++) {
      f32x4 z = {0.f, 0.f, 0.f, 0.f};
      acc[m][n] = z;
    }
  bf16x8 a[4][2], b[4][2];

  // prologue: stage B0(0),A0(0),B1(0),A1(0),B0(1),A0(1); gate first 4.
  STAGE_B(0, 0); STAGE_A(0, 0); STAGE_B(0, 1); STAGE_A(0, 1);
  STAGE_B(1, 0); STAGE_A(1, 0);
  asm volatile("s_waitcnt vmcnt(4)" ::: "memory");
  __builtin_amdgcn_s_barrier();

#pragma unroll
  for (int kt = 0; kt < 8; ++kt) {
    const int abase = ((kt & 1) * 2 + wr) * 8192;
    const int bbase = 32768 + ((kt & 1) * 2 + (wc >> 1)) * 8192 + (wc & 1) * 4096;

    // ---- phase 0: read A m0-3 + B n0-1; stage B hi(kt+1); MFMA q(m0-3,n0-1)
#pragma unroll
    for (int m = 0; m < 4; ++m)
#pragma unroll
      for (int kk = 0; kk < 2; ++kk)
        a[m][kk] = *(const bf16x8*)&lds[abase + (m * 16 + fr) * 64 + ((kk * 32 + g * 8) ^ xr)];
#pragma unroll
    for (int n = 0; n < 2; ++n)
#pragma unroll
      for (int kk = 0; kk < 2; ++kk)
        b[n][kk] = *(const bf16x8*)&lds[bbase + (n * 16 + fr) * 64 + ((kk * 32 + g * 8) ^ xr)];
    if (kt < 7) STAGE_B(kt + 1, 1);
    __builtin_amdgcn_s_barrier();
    asm volatile("s_waitcnt lgkmcnt(0)" ::: "memory");
    __builtin_amdgcn_s_setprio(1);
#pragma unroll
    for (int m = 0; m < 4; ++m)
#pragma unroll
      for (int n = 0; n < 2; ++n)
#pragma unroll
        for (int kk = 0; kk < 2; ++kk)
          acc[m][n] = __builtin_amdgcn_mfma_f32_16x16x32_bf16(a[m][kk], b[n][kk], acc[m][n], 0, 0, 0);
    __builtin_amdgcn_s_setprio(0);
    __builtin_amdgcn_s_barrier();

    // ---- phase 1: read B n2-3; stage A hi(kt+1); MFMA q(m0-3,n2-3)
#pragma unroll
    for (int n = 0; n < 2; ++n)
#pragma unroll
      for (int kk = 0; kk < 2; ++kk)
        b[2 + n][kk] = *(const bf16x8*)&lds[bbase + ((n + 2) * 16 + fr) * 64 + ((kk * 32 + g * 8) ^ xr)];
    if (kt < 7) STAGE_A(kt + 1, 1);
    __builtin_amdgcn_s_barrier();
    asm volatile("s_waitcnt lgkmcnt(0)" ::: "memory");
    __builtin_amdgcn_s_setprio(1);
#pragma unroll
    for (int m = 0; m < 4; ++m)
#pragma unroll
      for (int n = 0; n < 2; ++n)
#pragma unroll
        for (int kk = 0; kk < 2; ++kk)
          acc[m][2 + n] = __builtin_amdgcn_mfma_f32_16x16x32_bf16(a[m][kk], b[2 + n][kk], acc[m][2 + n], 0, 0, 0);
    __builtin_amdgcn_s_setprio(0);
    __builtin_amdgcn_s_barrier();

    // ---- phase 2: read A m4-7 (reuse regs); stage B lo(kt+2); MFMA q(m4-7,n2-3)
#pragma unroll
    for (int m = 0; m < 4; ++m)
#pragma unroll
      for (int kk = 0; kk < 2; ++kk)
        a[m][kk] = *(const bf16x8*)&lds[abase + ((m + 4) * 16 + fr) * 64 + ((kk * 32 + g * 8) ^ xr)];
    if (kt < 6) STAGE_B(kt + 2, 0);
    __builtin_amdgcn_s_barrier();
    asm volatile("s_waitcnt lgkmcnt(0)" ::: "memory");
    __builtin_amdgcn_s_setprio(1);
#pragma unroll
    for (int m = 0; m < 4; ++m)
#pragma unroll
      for (int n = 0; n < 2; ++n)
#pragma unroll
        for (int kk = 0; kk < 2; ++kk)
          acc[4 + m][2 + n] = __builtin_amdgcn_mfma_f32_16x16x32_bf16(a[m][kk], b[2 + n][kk], acc[4 + m][2 + n], 0, 0, 0);
    __builtin_amdgcn_s_setprio(0);
    __builtin_amdgcn_s_barrier();

    // ---- phase 3: stage A lo(kt+2); counted vmcnt gate; MFMA q(m4-7,n0-1)
    if (kt < 6) {
      STAGE_A(kt + 2, 0);
      asm volatile("s_waitcnt vmcnt(4)" ::: "memory");
    } else {
      asm volatile("s_waitcnt vmcnt(0)" ::: "memory");
    }
    __builtin_amdgcn_s_barrier();
    __builtin_amdgcn_s_setprio(1);
#pragma unroll
    for (int m = 0; m < 4; ++m)
#pragma unroll
      for (int n = 0; n < 2; ++n)
#pragma unroll
        for (int kk = 0; kk < 2; ++kk)
          acc[4 + m][n] = __builtin_amdgcn_mfma_f32_16x16x32_bf16(a[m][kk], b[n][kk], acc[4 + m][n], 0, 0, 0);
    __builtin_amdgcn_s_setprio(0);
    __builtin_amdgcn_s_barrier();
  }
#undef STAGE_A
#undef STAGE_B

  // epilogue: direct stores. rows row0+wr*128+m*16+g*4+j, cols col0+wc*64+n*16+fr
  const long rbase = row0 + wr * 128;
  if constexpr (SPLIT3) {
    const int bufi = (int)(col0 >> 9);  // 256-tile never straddles 512 boundary
    u16* ob = bufi == 0 ? (u16*)Out : (bufi == 1 ? OutK : OutV);
    const bool dorelu = bufi < 2;
    const long cbase = (col0 & 511) + wc * 64;
#pragma unroll
    for (int m = 0; m < 8; ++m)
#pragma unroll
      for (int n = 0; n < 4; ++n)
#pragma unroll
        for (int j = 0; j < 4; ++j) {
          long gr = rbase + m * 16 + g * 4 + j;
          long gc = cbase + n * 16 + fr;
          float v = acc[m][n][j];
          if (dorelu) v = fmaxf(v, 0.f);
          ob[gr * 512 + gc] = f2bf(v);
        }
  } else {
    const long cbase = col0 + wc * 64;
#pragma unroll
    for (int m = 0; m < 8; ++m)
#pragma unroll
      for (int n = 0; n < 4; ++n)
#pragma unroll
        for (int j = 0; j < 4; ++j) {
          long gr = rbase + m * 16 + g * 4 + j;
          long gc = cbase + n * 16 + fr;
          float v = acc[m][n][j];
          if constexpr (FINAL) {
            ((float*)Out)[gr * N_DIM + gc] = v + bias[gc];
          } else {
            ((u16*)Out)[gr * N_DIM + gc] = f2bf(v);
          }
        }
  }
}

// ---------------------------------------------------------------------------
// Kernel 2 (MFMA): vk[b,h,c,d] = sum_n v[n,h,c]*k[n,h,d], row 32 = sum_n k.
// ---------------------------------------------------------------------------
__global__ __launch_bounds__(256) void vk_kernel(const u16* __restrict__ kb,
                                                 const u16* __restrict__ vb,
                                                 float* __restrict__ vk) {
  __shared__ u16 tile[4][64 * 64];   // 32 KB
  __shared__ float red[1056];        // 4.2 KB block accumulator

  const int tid = threadIdx.x;
  const int lane = tid & 63;
  const int w = tid >> 6;

  for (int i = tid; i < 1056; i += 256) red[i] = 0.f;
  __syncthreads();

  const int bh = blockIdx.x >> 4;
  const int split = blockIdx.x & 15;
  const int b = bh >> 4, h = bh & 15;

  const int s = lane & 7;   // column segment: 0-3 -> k, 4-7 -> v
  const int rl = lane >> 3; // row within 8-row staging group
  const u16* src = (s & 4) ? vb : kb;
  const size_t gbase = (size_t)b * SEQ * 512 + h * 32 + (s & 3) * 8;

  f32x4 acc[2][2];
  f32x4 accs[2];
#pragma unroll
  for (int tc = 0; tc < 2; tc++) {
    f32x4 z = {0.f, 0.f, 0.f, 0.f};
    accs[tc] = z;
#pragma unroll
    for (int td = 0; td < 2; td++) acc[tc][td] = z;
  }
  bf16x8 ones;
#pragma unroll
  for (int j = 0; j < 8; j++) ones[j] = (short)0x3F80;  // bf16 1.0

  const int m = lane & 15;
  const int g = lane >> 4;
  u16* tw = tile[w];
  const int n0w = split * 1024 + w * 256;

  for (int t = 0; t < 4; ++t) {
    const int nt = n0w + t * 64;
#pragma unroll
    for (int p = 0; p < 8; ++p)
      async16(src + gbase + (size_t)(nt + p * 8 + rl) * 512, &tw[p * 512]);
    asm volatile("s_waitcnt vmcnt(0)" ::: "memory");
#pragma unroll
    for (int kk = 0; kk < 2; ++kk) {
      bf16x8 av[2], bk[2];
#pragma unroll
      for (int tc = 0; tc < 2; tc++)
#pragma unroll
        for (int j = 0; j < 8; j++)
          av[tc][j] = (short)tw[(kk * 32 + g * 8 + j) * 64 + 32 + tc * 16 + m];
#pragma unroll
      for (int td = 0; td < 2; td++)
#pragma unroll
        for (int j = 0; j < 8; j++)
          bk[td][j] = (short)tw[(kk * 32 + g * 8 + j) * 64 + td * 16 + m];
#pragma unroll
      for (int tc = 0; tc < 2; tc++)
#pragma unroll
        for (int td = 0; td < 2; td++)
          acc[tc][td] = __builtin_amdgcn_mfma_f32_16x16x32_bf16(av[tc], bk[td], acc[tc][td], 0, 0, 0);
#pragma unroll
      for (int td = 0; td < 2; td++)
        accs[td] = __builtin_amdgcn_mfma_f32_16x16x32_bf16(ones, bk[td], accs[td], 0, 0, 0);
    }
  }

#pragma unroll
  for (int tc = 0; tc < 2; tc++)
#pragma unroll
    for (int td = 0; td < 2; td++)
#pragma unroll
      for (int j = 0; j < 4; j++)
        atomicAdd(&red[(tc * 16 + g * 4 + j) * 32 + td * 16 + m], acc[tc][td][j]);
  if (lane < 16) {
#pragma unroll
    for (int td = 0; td < 2; td++)
      atomicAdd(&red[1024 + td * 16 + lane], accs[td][0]);
  }
  __syncthreads();
  float* dst = vk + (size_t)bh * 1056;
  for (int i = tid; i < 1056; i += 256) atomicAdd(&dst[i], red[i]);
}

// ---------------------------------------------------------------------------
// Kernel 3: vk_q + divide -> proj_input (bf16). CHUNKED: 1024 blocks, each
// loads the 8-head vk table into LDS once and processes 4 x 32-row chunks
// (was 4096 blocks x 1 chunk -> 4x table reload + 4x block-start latency).
// ---------------------------------------------------------------------------
__global__ __launch_bounds__(256) void vkq_kernel(const u16* __restrict__ qb,
                                                  const float* __restrict__ vk,
                                                  u16* __restrict__ pi) {
  __shared__ float vkl[8 * 1056];  // 33.8 KB
  __shared__ u16 ob[32 * 256];     // 16 KB output bounce

  const int tid = threadIdx.x;
  const int grp = blockIdx.x & 127;        // 128 groups of 128 rows
  const int hh = (blockIdx.x >> 7) & 1;
  const int b = blockIdx.x >> 8;

  const float* vg = vk + (size_t)(b * NH + hh * 8) * 1056;
  for (int i = tid; i < 8 * 1056; i += 256) vkl[i] = vg[i];
  __syncthreads();

  const int nl = tid & 31;
  const int hl = tid >> 5;
  const float* vkh = &vkl[hl * 1056];

  for (int c4 = 0; c4 < 4; ++c4) {
    const int n0 = grp * 128 + c4 * 32;

    const u16* qp = qb + ((size_t)b * SEQ + n0 + nl) * 512 + (hh * 8 + hl) * 32;
    float qf[32];
#pragma unroll
    for (int s2 = 0; s2 < 4; ++s2) {
      bf16x8 qv = *(const bf16x8*)(qp + s2 * 8);
#pragma unroll
      for (int j = 0; j < 8; ++j) qf[s2 * 8 + j] = bf2f((u16)qv[j]);
    }

    float num[32];
#pragma unroll
    for (int c = 0; c < 32; ++c) {
      float a = 0.f;
#pragma unroll
      for (int d4 = 0; d4 < 8; ++d4) {
        f32x4 vv = *(const f32x4*)&vkh[c * 32 + d4 * 4];
        a = fmaf(qf[d4 * 4 + 0], vv[0], a);
        a = fmaf(qf[d4 * 4 + 1], vv[1], a);
        a = fmaf(qf[d4 * 4 + 2], vv[2], a);
        a = fmaf(qf[d4 * 4 + 3], vv[3], a);
      }
      num[c] = a;
    }
    float den = 0.f;
#pragma unroll
    for (int d4 = 0; d4 < 8; ++d4) {
      f32x4 vv = *(const f32x4*)&vkh[32 * 32 + d4 * 4];
      den = fmaf(qf[d4 * 4 + 0], vv[0], den);
      den = fmaf(qf[d4 * 4 + 1], vv[1], den);
      den = fmaf(qf[d4 * 4 + 2], vv[2], den);
      den = fmaf(qf[d4 * 4 + 3], vv[3], den);
    }
    const float r = 1.0f / (den + 1e-15f);
#pragma unroll
    for (int c = 0; c < 32; ++c) ob[nl * 256 + hl * 32 + c] = f2bf(num[c] * r);
    __syncthreads();

    u16* pg = pi + ((size_t)b * SEQ + n0) * CH + hh * 256;
    for (int i = tid; i < 1024; i += 256) {
      const int n = i >> 5;
      const int u = i & 31;
      *(bf16x8*)(pg + (size_t)n * CH + u * 8) = *(const bf16x8*)&ob[i * 8];
    }
    __syncthreads();  // ob reused next chunk
  }
}

// ---------------------------------------------------------------------------
extern "C" void kernel_launch(void* const* d_in, const int* in_sizes, int n_in,
                              void* d_out, int out_size, void* d_ws, size_t ws_size,
                              hipStream_t stream) {
  const float* x = (const float*)d_in[0];
  const float* qw = (const float*)d_in[1];
  const float* pw = (const float*)d_in[2];
  const float* bias = (const float*)d_in[3];

  char* ws = (char*)d_ws;
  u16* qb = (u16*)(ws);                       // 65536*512*2 = 67108864 B
  u16* kb = (u16*)(ws + 67108864);            // 67108864 B
  u16* vb = (u16*)(ws + 134217728);           // 67108864 B
  u16* xb = (u16*)(ws + 201326592);           // 67108864 B
  u16* qwb = (u16*)(ws + 268435456);          // 1536*512*2 = 1572864 B
  u16* pwb = (u16*)(ws + 270008320);          // 512*512*2  =  524288 B
  float* vk = (float*)(ws + 270532608);       // 64*1056*4  =  270336 B
  u16* pi = xb;  // alias: x_bf16 dead after QKV GEMM; reuse for proj_input

  prep_kernel<<<2048, 256, 0, stream>>>(x, qw, pw, xb, qwb, pwb, vk);
  gemm8p_kernel<QKVC, true, false>
      <<<dim3(QKVC / 256, MROWS / 256), 512, 0, stream>>>(xb, qwb, qb, kb, vb, nullptr);
  vk_kernel<<<NB * NH * 16, 256, 0, stream>>>(kb, vb, vk);
  vkq_kernel<<<NB * 2 * (SEQ / 128), 256, 0, stream>>>(qb, vk, pi);
  gemm8p_kernel<CH, false, true>
      <<<dim3(CH / 256, MROWS / 256), 512, 0, stream>>>(pi, pwb, d_out, nullptr, nullptr, bias);
}